// Round 1
// 306.890 us; speedup vs baseline: 1.0099x; 1.0099x over previous
//
#include <hip/hip_runtime.h>
#include <math.h>

// MMD, Gaussian kernel, bandwidth=512. X:[8192,512] Y:[8192,512] fp32.
// S_AB = sum_ij exp(-||a_i-b_j||^2/512); final combine emulates the
// reference's fp32 logsumexp->exp->combine path (see finalize_kernel).
//
// Architecture (validated R9-R11): fp16 single-product MFMA S-pass (S needs
// << 1 fp32 lse cell = 17 units of 9.1e6) + bit-exact reproduction of the
// R5 bf16-split 3-product d2 min for m (lse cell shifts with m at sub-ulp
// granularity -> m must be the exact winning bits; XX/YY via 32x32 diag
// self-tiles, XY via banded refine).
// Round-12: 4 k-steps (32 KB) per LDS buffer; XY refine at 1024 threads.
// Round-13: counted-vmcnt pipeline (T3/T4). The R12 loop's __syncthreads()
// emitted s_waitcnt vmcnt(0) -> every interval drained the 16 DMAs just
// issued for the NEXT quad (MfmaUtil pinned at 34%, interval ~6900cy vs
// 2048cy of MFMA work). New schedule per interval: issue 16 vmem (window
// invariant, "memory"-fenced) -> s_waitcnt vmcnt(16) (prev window's 16 are
// the FIFO-oldest -> landed) -> s_barrier -> compute -> lgkmcnt(0) +
// s_barrier (buffer free). Prefetch stays in flight across both barriers.
// MFMA issue order unchanged -> all sums/mins bit-identical to R12.

#define D      512
#define BTM    128
#define BTN    256
#define BK     16
#define KSTEPS (D / BK)

// 16B-unit offsets in the XY refine kernel's LDS (R5 layout [point*2+khalf])
#define AHI 0
#define ALO 256
#define BHI 512
#define BLO 1024

typedef _Float16 half8 __attribute__((ext_vector_type(8)));
typedef __attribute__((ext_vector_type(8)))  short  short8;   // 8 bf16
typedef __attribute__((ext_vector_type(16))) float  f32x16;   // 32x32 acc

union U4H8 { uint4 u; half8 h; };
union U4S8 { uint4 u; short8 s; };

__device__ __forceinline__ unsigned short bf16_rne(float x) {
    unsigned u = __float_as_uint(x);
    return (unsigned short)((u + 0x7fffu + ((u >> 16) & 1u)) >> 16);
}
__device__ __forceinline__ float bf16_f32(unsigned short b) {
    return __uint_as_float(((unsigned)b) << 16);
}
__device__ __forceinline__ void split8(const float v[8], uint4& hi, uint4& lo) {
    unsigned h[8], l[8];
    #pragma unroll
    for (int j = 0; j < 8; j++) {
        unsigned short bh = bf16_rne(v[j]);
        float r = v[j] - bf16_f32(bh);          // exact (Sterbenz)
        unsigned short bl = bf16_rne(r);
        h[j] = bh; l[j] = bl;
    }
    hi.x = h[0] | (h[1] << 16); hi.y = h[2] | (h[3] << 16);
    hi.z = h[4] | (h[5] << 16); hi.w = h[6] | (h[7] << 16);
    lo.x = l[0] | (l[1] << 16); lo.y = l[2] | (l[3] << 16);
    lo.z = l[4] | (l[5] << 16); lo.w = l[6] | (l[7] << 16);
}

// async global->LDS, 16B per lane
__device__ __forceinline__ void lds16(const uint4* g, uint4* l) {
    __builtin_amdgcn_global_load_lds(
        (const __attribute__((address_space(1))) void*)g,
        (__attribute__((address_space(3))) void*)(unsigned int)(uintptr_t)(void*)l,
        16, 0, 0);
}

__global__ void init_kernel(double* accum, unsigned* minkey) {
    if (threadIdx.x < 3) accum[threadIdx.x] = 0.0;
    if (threadIdx.x < 4) minkey[threadIdx.x] = 0xFFFFFFFFu;
}

// fp16 convert: src[npts][512] fp32 -> [kstep][p>>5][khalf][p&31] 16B units
__global__ __launch_bounds__(256)
void convert_h_kernel(const float* __restrict__ X, const float* __restrict__ Y,
                      uint4* __restrict__ Xh, uint4* __restrict__ Yh, int npts) {
    const float* src = blockIdx.z ? Y : X;
    uint4*       dst = blockIdx.z ? Yh : Xh;
    const int ks = blockIdx.y;
    const int p  = blockIdx.x * 256 + threadIdx.x;
    if (p >= npts) return;
    const float* s = src + (size_t)p * D + ks * BK;
    float v[16];
    *(float4*)&v[0]  = *(const float4*)(s);
    *(float4*)&v[4]  = *(const float4*)(s + 4);
    *(float4*)&v[8]  = *(const float4*)(s + 8);
    *(float4*)&v[12] = *(const float4*)(s + 12);
    U4H8 a, b;
    #pragma unroll
    for (int j = 0; j < 8; j++) { a.h[j] = (_Float16)v[j]; b.h[j] = (_Float16)v[8 + j]; }
    size_t u = (size_t)ks * npts * 2 + (size_t)(p >> 5) * 64 + (p & 31);
    dst[u] = a.u; dst[u + 32] = b.u;
}

__global__ __launch_bounds__(256)
void row_norms_kernel(const float* __restrict__ X, const float* __restrict__ Y,
                      float* __restrict__ X2, float* __restrict__ Y2, int N, int M) {
    const int wave = threadIdx.x >> 6;
    const int lane = threadIdx.x & 63;
    const int row  = blockIdx.x * 4 + wave;
    const float* src; float* dst; int r;
    if (row < N)          { src = X; dst = X2; r = row; }
    else if (row < N + M) { src = Y; dst = Y2; r = row - N; }
    else return;
    const float* p = src + (size_t)r * D;
    float s = 0.f;
    #pragma unroll
    for (int c = 0; c < D; c += 64) {
        float v = p[c + lane];
        s = fmaf(v, v, s);
    }
    #pragma unroll
    for (int off = 32; off > 0; off >>= 1) s += __shfl_down(s, off);
    if (lane == 0) dst[r] = s;
}

__device__ inline unsigned float_key(float f) {
    unsigned u = __float_as_uint(f);
    return (u & 0x80000000u) ? ~u : (u | 0x80000000u);
}
__device__ inline float key_float(unsigned k) {
    return __uint_as_float((k & 0x80000000u) ? (k ^ 0x80000000u) : ~k);
}

// ---- XX/YY m: R5-bit-exact diag d2 via 32x32 self-tiles (fused X+Y) ------
__global__ __launch_bounds__(256)
void diag_min_bits_kernel(const float* __restrict__ X, const float* __restrict__ Y,
                          const float* __restrict__ X2, const float* __restrict__ Y2,
                          unsigned* __restrict__ minkey, int ngx) {
    int b = blockIdx.x;
    const float *src, *n2; int zidx;
    if (b < ngx) { src = X; n2 = X2; zidx = 0; }
    else         { src = Y; n2 = Y2; zidx = 2; b -= ngx; }

    const int tid  = threadIdx.x;
    const int wave = tid >> 6, lane = tid & 63;
    const int grp  = b * 4 + wave;                // 32-point group id
    const int fp   = lane & 31, fh = lane >> 5;
    const int pt   = grp * 32 + fp;
    const float* s = src + (size_t)pt * D + fh * 8;

    f32x16 acc;
    #pragma unroll
    for (int i = 0; i < 16; i++) acc[i] = 0.f;

    for (int ks = 0; ks < KSTEPS; ks++) {
        float v[8];
        *(float4*)&v[0] = *(const float4*)(s + ks * BK);
        *(float4*)&v[4] = *(const float4*)(s + ks * BK + 4);
        U4S8 hi, lo;
        split8(v, hi.u, lo.u);
        short8 ah = hi.s, al = lo.s;
        // R5 order: hh, h*lB, lA*h (A-frag == B-frag here)
        acc = __builtin_amdgcn_mfma_f32_32x32x16_bf16(ah, ah, acc, 0, 0, 0);
        acc = __builtin_amdgcn_mfma_f32_32x32x16_bf16(ah, al, acc, 0, 0, 0);
        acc = __builtin_amdgcn_mfma_f32_32x32x16_bf16(al, ah, acc, 0, 0, 0);
    }

    float dmin = 1e30f;
    if (fh == ((fp >> 2) & 1)) {
        int r = (fp & 3) + 4 * (fp >> 3);
        float av = acc[r];
        float rn = n2[pt];
        float cn = rn;
        float d2 = rn + cn - 2.0f * av;           // exact: contraction-safe
        dmin = d2;
    }
    #pragma unroll
    for (int off = 32; off > 0; off >>= 1) dmin = fminf(dmin, __shfl_down(dmin, off));
    __shared__ float wm[4];
    __shared__ int   wz[4];
    if (lane == 0) { wm[wave] = dmin; wz[wave] = zidx; }
    __syncthreads();
    if (tid == 0)
        atomicMin(&minkey[wz[0]],
                  float_key(fminf(fminf(wm[0], wm[1]), fminf(wm[2], wm[3]))));
}

// ---------- fp16 S-pass: grid (64,32,3): z=0 XX (sym), 1 XY, 2 YY ----------
__global__ __launch_bounds__(256, 2)
void pair_exp_sum_kernel(const uint4* __restrict__ Xh, const uint4* __restrict__ Yh,
                         const float* __restrict__ X2, const float* __restrict__ Y2,
                         double* __restrict__ accum, float* __restrict__ bmin,
                         int N, int M) {
    const int z = blockIdx.z;
    const uint4 *Ah, *Bh; const float *An, *Bn; bool sym; int na, nb;
    if (z == 0)      { Ah = Xh; Bh = Xh; An = X2; Bn = X2; sym = true;  na = N; nb = N; }
    else if (z == 1) { Ah = Xh; Bh = Yh; An = X2; Bn = Y2; sym = false; na = N; nb = M; }
    else             { Ah = Yh; Bh = Yh; An = Y2; Bn = Y2; sym = true;  na = M; nb = M; }
    const int bi = blockIdx.x, bj = blockIdx.y;
    if (sym && (2 * bj + 1) < bi) return;        // both 128-col halves below diag

    __shared__ uint4  smem[2][2048];             // 2 bufs x 32 KB (4 ksteps each)
    __shared__ float  smN[BTM + BTN];
    __shared__ double wsum[4];
    __shared__ float  wmin[4];

    const int tid  = threadIdx.x;
    const int wave = tid >> 6, lane = tid & 63;
    const int wy = wave >> 1, wx = wave & 1;     // 2x2 waves, each 64x128
    const int row0 = bi * BTM, col0 = bj * BTN;

    if (tid < BTM) smN[tid] = An[row0 + tid];
    smN[BTM + tid] = Bn[col0 + tid];

    const int wl = wave * 64 + lane;
    const size_t strideA = (size_t)na * 2;       // 16B units per kstep
    const size_t strideB = (size_t)nb * 2;
    const uint4* gB0 = Bh + (size_t)(col0 >> 5) * 64 + wl;
    const uint4* gB1 = gB0 + 256;
    const half8* gA0 = (const half8*)Ah + ((size_t)(row0 >> 5) + 2 * wy) * 64 + lane;
    const half8* gA1 = gA0 + 64;

    f32x16 acc[2][4];
    #pragma unroll
    for (int g = 0; g < 2; g++)
        #pragma unroll
        for (int c = 0; c < 4; c++)
            #pragma unroll
            for (int i = 0; i < 16; i++) acc[g][c][i] = 0.f;

    // stage FOUR k-steps (32 KB) into one buffer; kstep j at unit j*512
    auto stage4 = [&](int buf, int ks) {
        #pragma unroll
        for (int j = 0; j < 4; j++) {
            lds16(gB0 + (size_t)(ks + j) * strideB, &smem[buf][j * 512 + wl]);
            lds16(gB1 + (size_t)(ks + j) * strideB, &smem[buf][j * 512 + 256 + wl]);
        }
    };
    half8 Af[8][2];                              // [slot][g]; 4 slots per buffer
    auto loadA4 = [&](int ks, int s) {
        #pragma unroll
        for (int j = 0; j < 4; j++) {
            Af[s + j][0] = gA0[(size_t)(ks + j) * strideA];
            Af[s + j][1] = gA1[(size_t)(ks + j) * strideA];
        }
    };
    auto computeK = [&](const uint4* base, int slot) {   // one kstep
        const half8* p = (const half8*)base;
        half8 bh[4];
        #pragma unroll
        for (int c = 0; c < 4; c++) bh[c] = p[(4 * wx + c) * 64 + lane];
        #pragma unroll
        for (int g = 0; g < 2; g++)
            #pragma unroll
            for (int c = 0; c < 4; c++)
                acc[g][c] = __builtin_amdgcn_mfma_f32_32x32x16_f16(Af[slot][g], bh[c], acc[g][c], 0, 0, 0);
    };

    // Counted-vmcnt schedule. Window invariant: each iteration issues exactly
    // 16 vmem ops (8 global_load_lds + 8 A-loads) bracketed by "memory"-
    // clobber fences -> at s_waitcnt vmcnt(16) the previous window's 16 are
    // the FIFO-oldest outstanding ops, so they (and only they) are drained.
    // The current window's prefetch stays in flight across both barriers.
    stage4(0, 0);
    loadA4(0, 0);

    #pragma unroll
    for (int it = 1; it < KSTEPS / 4; it++) {    // 7 intervals
        stage4(it & 1, 4 * it);                  // prefetch next quad (16 vmem)
        loadA4(4 * it, (it & 1) * 4);
        asm volatile("s_waitcnt vmcnt(16)" ::: "memory");   // prev quad landed (self)
        __builtin_amdgcn_s_barrier();                       // ... for all waves
        __builtin_amdgcn_sched_barrier(0);                  // pin ds_reads below
        const int pb = (it - 1) & 1, ps = pb * 4;
        computeK(&smem[pb][0],    ps + 0);       // ksteps 4(it-1)..4(it-1)+3
        computeK(&smem[pb][512],  ps + 1);
        computeK(&smem[pb][1024], ps + 2);
        computeK(&smem[pb][1536], ps + 3);
        asm volatile("s_waitcnt lgkmcnt(0)" ::: "memory");  // my ds_reads retired
        __builtin_amdgcn_s_barrier();                       // buffer pb free for all
    }
    asm volatile("s_waitcnt vmcnt(0)" ::: "memory");        // quad 7 + A(7) landed
    __builtin_amdgcn_s_barrier();
    __builtin_amdgcn_sched_barrier(0);
    computeK(&smem[1][0],    4);                 // ksteps 28..31
    computeK(&smem[1][512],  5);
    computeK(&smem[1][1024], 6);
    computeK(&smem[1][1536], 7);

    float wgt = 1.f;
    if (sym) {
        int cblk = 2 * bj + wx;
        wgt = (cblk > bi) ? 2.f : (cblk == bi ? 1.f : 0.f);
    }

    // C/D layout (m74/m101): col=lane&31, row=(reg&3)+8*(reg>>2)+4*(lane>>5)
    const int fp = lane & 31, fh = lane >> 5;
    double s = 0.0;
    float dmin = 1e30f;
    if (wgt != 0.f) {
        const float* rowN = &smN[64 * wy];
        const float* colN = &smN[BTM + 128 * wx];
        const float kC = -0.0028177637517362567f;   // -log2(e)/512
        #pragma unroll
        for (int g = 0; g < 2; g++)
            #pragma unroll
            for (int c = 0; c < 4; c++) {
                float cn = colN[32 * c + fp];
                float rs = 0.f;
                #pragma unroll
                for (int r = 0; r < 16; r++) {
                    int r32 = (r & 3) + 8 * (r >> 2) + 4 * fh;
                    float d2 = rowN[32 * g + r32] + cn - 2.0f * acc[g][c][r];
                    dmin = fminf(dmin, d2);
                    rs += exp2f(d2 * kC);            // v_exp_f32; args in [-4.2,0]
                }
                s += (double)rs;
            }
        s *= (double)wgt;
    }

    #pragma unroll
    for (int off = 32; off > 0; off >>= 1) {
        s += __shfl_down(s, off);
        dmin = fminf(dmin, __shfl_down(dmin, off));
    }
    if (lane == 0) { wsum[wave] = s; wmin[wave] = dmin; }
    __syncthreads();
    if (tid == 0) {
        atomicAdd(&accum[z], wsum[0] + wsum[1] + wsum[2] + wsum[3]);
        if (z == 1)                              // noisy (+-~0.05) block min
            bmin[bi * gridDim.y + bj] = fminf(fminf(wmin[0], wmin[1]),
                                              fminf(wmin[2], wmin[3]));
    }
}

__global__ __launch_bounds__(256)
void xy_gmin_kernel(const float* __restrict__ bmin, float* __restrict__ gmin, int nblk) {
    float m = 1e30f;
    for (int i = threadIdx.x; i < nblk; i += 256) m = fminf(m, bmin[i]);
    #pragma unroll
    for (int off = 32; off > 0; off >>= 1) m = fminf(m, __shfl_down(m, off));
    __shared__ float wm[4];
    if ((threadIdx.x & 63) == 0) wm[threadIdx.x >> 6] = m;
    __syncthreads();
    if (threadIdx.x == 0) gmin[0] = fminf(fminf(wm[0], wm[1]), fminf(wm[2], wm[3]));
}

// ---------- XY refine: R5-bit-exact bf16-split 3-product d2 min -----------
// 1024 threads / 16 waves; wave w owns row-group gy=w&3 (32 rows) and col
// groups 2*(w>>2), 2*(w>>2)+1. Per-accumulator k-chain (hh,hl,lh per kstep,
// ks 0..31) identical to R5 -> same d2 bits; ~4x less serial latency.
__global__ __launch_bounds__(1024)
void refine_min_kernel(const float* __restrict__ A, const float* __restrict__ B,
                       const float* __restrict__ An, const float* __restrict__ Bn,
                       const float* __restrict__ bmin, const float* __restrict__ gmin,
                       unsigned* __restrict__ minkey, int zidx) {
    const int bi = blockIdx.x;
    const int bj = blockIdx.y;
    if (!(bmin[bi * gridDim.y + bj] < gmin[0] + 0.5f)) return;
    const int row0 = bi * BTM, col0 = bj * BTN;

    __shared__ uint4 smem[1536];                 // Ahi|Alo|Bhi|Blo (R5 layout)
    __shared__ float smN[BTM + BTN];
    __shared__ float wmin[16];

    const int tid  = threadIdx.x;
    const int wave = tid >> 6, lane = tid & 63;
    const int gy = wave & 3, cg0 = 2 * (wave >> 2);
    if (tid < BTM) smN[tid] = An[row0 + tid];
    if (tid < BTN) smN[BTM + tid] = Bn[col0 + tid];

    const int fp = lane & 31, fh = lane >> 5;
    const int au = (32 * gy + fp) * 2 + fh;
    int bu[2];
    #pragma unroll
    for (int c = 0; c < 2; c++) bu[c] = (32 * (cg0 + c) + fp) * 2 + fh;

    f32x16 acc[2];
    #pragma unroll
    for (int c = 0; c < 2; c++)
        #pragma unroll
        for (int i = 0; i < 16; i++) acc[c][i] = 0.f;

    for (int ks = 0; ks < KSTEPS; ks++) {
        __syncthreads();                         // prev-step LDS reads done
        if (tid < 256) {                         // A: unit tid
            const float* s = A + (size_t)(row0 + (tid >> 1)) * D + ks * BK + (tid & 1) * 8;
            float v[8];
            *(float4*)&v[0] = *(const float4*)s;
            *(float4*)&v[4] = *(const float4*)(s + 4);
            uint4 hi, lo; split8(v, hi, lo);
            smem[AHI + tid] = hi; smem[ALO + tid] = lo;
        } else if (tid < 768) {                  // B: unit tid-256
            int u = tid - 256;
            const float* s = B + (size_t)(col0 + (u >> 1)) * D + ks * BK + (u & 1) * 8;
            float v[8];
            *(float4*)&v[0] = *(const float4*)s;
            *(float4*)&v[4] = *(const float4*)(s + 4);
            uint4 hi, lo; split8(v, hi, lo);
            smem[BHI + u] = hi; smem[BLO + u] = lo;
        }
        __syncthreads();
        {   // per-acc chain: hh, hl, lh (matches R5 acc[g][c] chain order)
            const short8* p = (const short8*)&smem[0];
            short8 ah = p[AHI + au], al = p[ALO + au];
            short8 bh[2], bl[2];
            #pragma unroll
            for (int c = 0; c < 2; c++) { bh[c] = p[BHI + bu[c]]; bl[c] = p[BLO + bu[c]]; }
            #pragma unroll
            for (int c = 0; c < 2; c++)
                acc[c] = __builtin_amdgcn_mfma_f32_32x32x16_bf16(ah, bh[c], acc[c], 0, 0, 0);
            #pragma unroll
            for (int c = 0; c < 2; c++)
                acc[c] = __builtin_amdgcn_mfma_f32_32x32x16_bf16(ah, bl[c], acc[c], 0, 0, 0);
            #pragma unroll
            for (int c = 0; c < 2; c++)
                acc[c] = __builtin_amdgcn_mfma_f32_32x32x16_bf16(al, bh[c], acc[c], 0, 0, 0);
        }
    }

    float dmin = 1e30f;
    const float* rowN = &smN[32 * gy];
    #pragma unroll
    for (int c = 0; c < 2; c++) {
        float cn = smN[BTM + 32 * (cg0 + c) + fp];
        #pragma unroll
        for (int r = 0; r < 16; r++) {
            int r32 = (r & 3) + 8 * (r >> 2) + 4 * fh;
            float d2 = rowN[r32] + cn - 2.0f * acc[c][r];
            dmin = fminf(dmin, d2);
        }
    }

    #pragma unroll
    for (int off = 32; off > 0; off >>= 1) dmin = fminf(dmin, __shfl_down(dmin, off));
    if (lane == 0) wmin[wave] = dmin;
    __syncthreads();
    if (tid == 0) {
        float m = wmin[0];
        #pragma unroll
        for (int w = 1; w < 16; w++) m = fminf(m, wmin[w]);
        atomicMin(&minkey[zidx], float_key(m));
    }
}

__global__ void finalize_kernel(const double* __restrict__ accum,
                                const unsigned* __restrict__ minkey,
                                float* __restrict__ out, int N, int M) {
    if (threadIdx.x == 0 && blockIdx.x == 0) {
        float Sp[3];
        #pragma unroll
        for (int z = 0; z < 3; z++) {
            float m = key_float(minkey[z]) * (-1.0f / 512.0f);
            double Sshift = accum[z] * exp(-(double)m);
            float r = (float)log(Sshift);        // correctly-rounded f32 log
            float lse = r + m;                   // fp32 add, as jax
            Sp[z] = (float)exp((double)lse);     // correctly-rounded f32 exp
        }
        float nf  = (float)N, mf = (float)M;
        float nn1 = (float)((double)N * (double)(N - 1));
        float mm1 = (float)((double)M * (double)(M - 1));
        float nm  = (float)((double)N * (double)M);
        float xx = (Sp[0] - nf) / nn1;
        float xy =  Sp[1]       / nm;
        float yy = (Sp[2] - mf) / mm1;
        out[0] = xx - 2.0f * xy + yy;
    }
}

extern "C" void kernel_launch(void* const* d_in, const int* in_sizes, int n_in,
                              void* d_out, int out_size, void* d_ws, size_t ws_size,
                              hipStream_t stream) {
    const float* X = (const float*)d_in[0];
    const float* Y = (const float*)d_in[1];
    const int N = in_sizes[0] / D;
    const int M = in_sizes[1] / D;
    const int gx = N / BTM, gy = M / BTN;        // 64 x 32

    double*   accum  = (double*)d_ws;
    unsigned* minkey = (unsigned*)((char*)d_ws + 32);
    float*    gmin   = (float*)((char*)d_ws + 48);
    float*    X2     = (float*)((char*)d_ws + 64);
    float*    Y2     = X2 + N;
    float*    bmin   = Y2 + M;
    size_t off = (64 + (size_t)(N + M) * 4 + (size_t)gx * gy * 4 + 255) & ~(size_t)255;
    size_t asz = (size_t)N * D * 2;
    uint4* Xh = (uint4*)((char*)d_ws + off);
    uint4* Yh = (uint4*)((char*)d_ws + off + asz);

    init_kernel<<<1, 64, 0, stream>>>(accum, minkey);

    row_norms_kernel<<<(N + M + 3) / 4, 256, 0, stream>>>(X, Y, X2, Y2, N, M);
    convert_h_kernel<<<dim3((N + 255) / 256, KSTEPS, 2), 256, 0, stream>>>(X, Y, Xh, Yh, N);

    diag_min_bits_kernel<<<N / 128 + M / 128, 256, 0, stream>>>(X, Y, X2, Y2, minkey, N / 128);

    dim3 grid(gx, gy, 3);
    pair_exp_sum_kernel<<<grid, 256, 0, stream>>>(Xh, Yh, X2, Y2, accum, bmin, N, M);

    xy_gmin_kernel<<<1, 256, 0, stream>>>(bmin, gmin, gx * gy);
    refine_min_kernel<<<dim3(gx, gy), 1024, 0, stream>>>(X, Y, X2, Y2, bmin, gmin,
                                                         minkey, 1);

    finalize_kernel<<<1, 64, 0, stream>>>(accum, minkey, (float*)d_out, N, M);
}